// Round 6
// baseline (253.061 us; speedup 1.0000x reference)
//
#include <hip/hip_runtime.h>
#include <hip/hip_fp16.h>

// Problem geometry: inputs (B=2, D=64, H=64, W=64, C=32) fp32, C innermost.
// Pass1: Sobel (VALID) -> mag = sqrt(gx^2+gy^2+gz^2) at 62^3 per (b,c)
// Pass2: Sobel on mag -> out = sqrt(gx^2+gy^2) + gz^2 at 60^3
// Result: mean(|out_pred - out_hr|) over 2*32*60^3 = 13,824,000 elems.
//
// R6: two fixes to the R4/R5 z-streaming skeleton (which was still ~35%
// VALUBusy / all-pipes-idle):
//  (a) uniform-base addressing: row pointers are wave-uniform (SGPR), the
//      only per-lane term is a single 32-bit lane offset; x-taps via load
//      immediate offsets. Kills the v_lshl_add_u64 storm (was ~2x the math).
//  (b) software pipelining: issue plane z+3's loads BEFORE emitting output z,
//      reduce after. Emit VALU overlaps load latency.
// Pass1: one volume/thread, YB=2 (VGPR ~80, high occupancy).
// Pass2: both volumes/thread (needed for diff), raw planes kept as half2.

constexpr int BDIM = 256;
constexpr size_t IN_B = 8388608;   // 64*64*64*32 elements per batch
constexpr int IN_D = 131072;       // 64*64*32
constexpr int IN_H = 2048;         // 64*32
constexpr int M = 62;              // mag spatial dim
constexpr int F = 60;              // final spatial dim
constexpr int C = 32;
constexpr int MROW = M * C;                      // 1984
constexpr size_t MAGSZ = (size_t)M * M * MROW;   // halves per buffer
constexpr size_t PLANE = (size_t)M * MROW;       // halves per mag z-plane

__device__ __forceinline__ float2 ld2(const float* p) {
    return *reinterpret_cast<const float2*>(p);
}

// ================= Pass 1: input -> fp16 magnitude, z-streamed =================
struct Raw1 { float2 v[12]; };                 // 4 rows x 3 x-taps
struct P1W  { float2 A[2], B[2], Cc[2]; };     // y-combined partials, 2 outputs

__device__ __forceinline__ void p1_issue(const float* __restrict__ pbase,
                                         int zplane, int y0, int lo, Raw1& r)
{
#pragma unroll
    for (int j = 0; j < 4; ++j) {
        const float* rowp = pbase + (size_t)zplane * IN_D + (size_t)(y0 + j) * IN_H;
        r.v[j * 3 + 0] = ld2(rowp + lo);
        r.v[j * 3 + 1] = ld2(rowp + lo + C);
        r.v[j * 3 + 2] = ld2(rowp + lo + 2 * C);
    }
}

__device__ __forceinline__ void p1_reduce(const Raw1& r, P1W& W)
{
    float2 SX[4], DX[4];
#pragma unroll
    for (int j = 0; j < 4; ++j) {
        float2 a = r.v[j * 3], b = r.v[j * 3 + 1], c = r.v[j * 3 + 2];
        SX[j] = make_float2(a.x + 2.f * b.x + c.x, a.y + 2.f * b.y + c.y);
        DX[j] = make_float2(c.x - a.x, c.y - a.y);
    }
#pragma unroll
    for (int k = 0; k < 2; ++k) {
        W.A[k]  = make_float2(SX[k].x + 2.f * SX[k+1].x + SX[k+2].x,
                              SX[k].y + 2.f * SX[k+1].y + SX[k+2].y);
        W.B[k]  = make_float2(SX[k+2].x - SX[k].x, SX[k+2].y - SX[k].y);
        W.Cc[k] = make_float2(DX[k].x + 2.f * DX[k+1].x + DX[k+2].x,
                              DX[k].y + 2.f * DX[k+1].y + DX[k+2].y);
    }
}

__device__ __forceinline__ void p1_emit(const P1W& W0, const P1W& W1, const P1W& W2,
                                        __half* __restrict__ mag, int z, int y0,
                                        int lo, bool xok)
{
    if (!xok) return;
#pragma unroll
    for (int k = 0; k < 2; ++k) {
        float gxx = W2.A[k].x - W0.A[k].x;
        float gxy = W2.A[k].y - W0.A[k].y;
        float gyx = W0.B[k].x + 2.f * W1.B[k].x + W2.B[k].x;
        float gyy = W0.B[k].y + 2.f * W1.B[k].y + W2.B[k].y;
        float gzx = W0.Cc[k].x + 2.f * W1.Cc[k].x + W2.Cc[k].x;
        float gzy = W0.Cc[k].y + 2.f * W1.Cc[k].y + W2.Cc[k].y;
        float mx = sqrtf(gxx * gxx + gyx * gyx + gzx * gzx);
        float my = sqrtf(gxy * gxy + gyy * gyy + gzy * gzy);
        *reinterpret_cast<__half2*>(mag + ((size_t)z * M + (y0 + k)) * MROW + lo)
            = __floats2half2_rn(mx, my);
    }
}

__global__ __launch_bounds__(BDIM) void sobel_mag_stream(
    const float* __restrict__ pred, const float* __restrict__ hr,
    __half* __restrict__ magbase, int bstart)
{
    const int xt = blockIdx.x & 3, yt = blockIdx.x >> 2;   // grid.x = 124 (4 x 31)
    const int zc = blockIdx.y;                             // [0,8): z-chunks of 8
    const int gz = blockIdx.z;                             // vol (+2 per batch)
    const int b  = bstart + (gz >> 1);
    const float* __restrict__ in  = (gz & 1) ? hr : pred;
    __half*      __restrict__ mag = magbase + (size_t)gz * MAGSZ;

    const int y0 = yt * 2;                // outputs y0, y0+1; rows y0..y0+3 (<64)
    const int z0 = zc * 8;
    const int zn = min(8, M - z0);        // 8, last chunk 6
    const int xraw = xt * 16 + (threadIdx.x >> 4);
    const bool xok = xraw < M;
    const int x = min(xraw, M - 1);
    const int lo = x * C + ((threadIdx.x & 15) << 1);

    const float* pbase = in + (size_t)b * IN_B;   // wave-uniform

    Raw1 r;
    P1W W0, W1, W2;
    p1_issue(pbase, z0 + 0, y0, lo, r); p1_reduce(r, W0);
    p1_issue(pbase, z0 + 1, y0, lo, r); p1_reduce(r, W1);
    p1_issue(pbase, z0 + 2, y0, lo, r); p1_reduce(r, W2);
    int z = 0;
    for (;;) {
        bool more = (z + 1 < zn);
        if (more) p1_issue(pbase, z0 + z + 3, y0, lo, r);
        p1_emit(W0, W1, W2, mag, z0 + z, y0, lo, xok);
        if (!more) break;
        ++z;
        p1_reduce(r, W0);
        more = (z + 1 < zn);
        if (more) p1_issue(pbase, z0 + z + 3, y0, lo, r);
        p1_emit(W1, W2, W0, mag, z0 + z, y0, lo, xok);
        if (!more) break;
        ++z;
        p1_reduce(r, W1);
        more = (z + 1 < zn);
        if (more) p1_issue(pbase, z0 + z + 3, y0, lo, r);
        p1_emit(W2, W0, W1, mag, z0 + z, y0, lo, xok);
        if (!more) break;
        ++z;
        p1_reduce(r, W2);
    }
}

// ============ Pass 2: mag -> final, diff, partial sums, z-streamed ============
struct Raw2 { __half2 v[12]; };                // packed: 12 VGPRs per volume
struct P2W  { float2 A[2], B[2], Cc[2]; };

__device__ __forceinline__ void p2_issue(const __half* __restrict__ mbase,
                                         int zplane, int y0, int lo, Raw2& r)
{
#pragma unroll
    for (int j = 0; j < 4; ++j) {
        const __half* rowp = mbase + (size_t)zplane * PLANE + (size_t)(y0 + j) * MROW;
        r.v[j * 3 + 0] = *reinterpret_cast<const __half2*>(rowp + lo);
        r.v[j * 3 + 1] = *reinterpret_cast<const __half2*>(rowp + lo + C);
        r.v[j * 3 + 2] = *reinterpret_cast<const __half2*>(rowp + lo + 2 * C);
    }
}

__device__ __forceinline__ void p2_reduce(const Raw2& r, P2W& W)
{
    float2 SX[4], DX[4];
#pragma unroll
    for (int j = 0; j < 4; ++j) {
        float2 a = __half22float2(r.v[j * 3]);
        float2 b = __half22float2(r.v[j * 3 + 1]);
        float2 c = __half22float2(r.v[j * 3 + 2]);
        SX[j] = make_float2(a.x + 2.f * b.x + c.x, a.y + 2.f * b.y + c.y);
        DX[j] = make_float2(c.x - a.x, c.y - a.y);
    }
#pragma unroll
    for (int k = 0; k < 2; ++k) {
        W.A[k]  = make_float2(SX[k].x + 2.f * SX[k+1].x + SX[k+2].x,
                              SX[k].y + 2.f * SX[k+1].y + SX[k+2].y);
        W.B[k]  = make_float2(SX[k+2].x - SX[k].x, SX[k+2].y - SX[k].y);
        W.Cc[k] = make_float2(DX[k].x + 2.f * DX[k+1].x + DX[k+2].x,
                              DX[k].y + 2.f * DX[k+1].y + DX[k+2].y);
    }
}

__device__ __forceinline__ void p2_emit(const P2W& P0, const P2W& P1, const P2W& P2,
                                        const P2W& H0, const P2W& H1, const P2W& H2,
                                        float& acc)
{
#pragma unroll
    for (int k = 0; k < 2; ++k) {
        float gxPx = P2.A[k].x - P0.A[k].x;
        float gxPy = P2.A[k].y - P0.A[k].y;
        float gyPx = P0.B[k].x + 2.f * P1.B[k].x + P2.B[k].x;
        float gyPy = P0.B[k].y + 2.f * P1.B[k].y + P2.B[k].y;
        float gzPx = P0.Cc[k].x + 2.f * P1.Cc[k].x + P2.Cc[k].x;
        float gzPy = P0.Cc[k].y + 2.f * P1.Cc[k].y + P2.Cc[k].y;
        float gxHx = H2.A[k].x - H0.A[k].x;
        float gxHy = H2.A[k].y - H0.A[k].y;
        float gyHx = H0.B[k].x + 2.f * H1.B[k].x + H2.B[k].x;
        float gyHy = H0.B[k].y + 2.f * H1.B[k].y + H2.B[k].y;
        float gzHx = H0.Cc[k].x + 2.f * H1.Cc[k].x + H2.Cc[k].x;
        float gzHy = H0.Cc[k].y + 2.f * H1.Cc[k].y + H2.Cc[k].y;
        float oPx = sqrtf(gxPx * gxPx + gyPx * gyPx) + gzPx * gzPx;
        float oPy = sqrtf(gxPy * gxPy + gyPy * gyPy) + gzPy * gzPy;
        float oHx = sqrtf(gxHx * gxHx + gyHx * gyHx) + gzHx * gzHx;
        float oHy = sqrtf(gxHy * gxHy + gyHy * gyHy) + gzHy * gzHy;
        acc += fabsf(oPx - oHx) + fabsf(oPy - oHy);
    }
}

__global__ __launch_bounds__(BDIM) void sobel2_stream(
    const __half* __restrict__ magbase, float* __restrict__ partial, int bstart)
{
    const int xt = blockIdx.x & 3, yt = blockIdx.x >> 2;   // grid.x = 120 (4 x 30)
    const int zc = blockIdx.y;                             // [0,10): chunks of 6
    const int b  = bstart + blockIdx.z;
    const __half* __restrict__ magP = magbase + (size_t)(2 * blockIdx.z) * MAGSZ;
    const __half* __restrict__ magH = magP + MAGSZ;

    const int y0 = yt * 2;                 // rows y0..y0+3 (< 62)
    const int z0 = zc * 6;
    const int zn = 6;
    const int xraw = xt * 16 + (threadIdx.x >> 4);
    const bool xok = xraw < F;
    const int x = min(xraw, F - 1);
    const int lo = x * C + ((threadIdx.x & 15) << 1);

    Raw2 rp, rh;
    P2W P0, P1, P2, H0, H1, H2;
    p2_issue(magP, z0 + 0, y0, lo, rp); p2_issue(magH, z0 + 0, y0, lo, rh);
    p2_reduce(rp, P0); p2_reduce(rh, H0);
    p2_issue(magP, z0 + 1, y0, lo, rp); p2_issue(magH, z0 + 1, y0, lo, rh);
    p2_reduce(rp, P1); p2_reduce(rh, H1);
    p2_issue(magP, z0 + 2, y0, lo, rp); p2_issue(magH, z0 + 2, y0, lo, rh);
    p2_reduce(rp, P2); p2_reduce(rh, H2);

    float acc = 0.f;
    int z = 0;
    for (;;) {
        bool more = (z + 1 < zn);
        if (more) { p2_issue(magP, z0 + z + 3, y0, lo, rp);
                    p2_issue(magH, z0 + z + 3, y0, lo, rh); }
        if (xok) p2_emit(P0, P1, P2, H0, H1, H2, acc);
        if (!more) break;
        ++z;
        p2_reduce(rp, P0); p2_reduce(rh, H0);
        more = (z + 1 < zn);
        if (more) { p2_issue(magP, z0 + z + 3, y0, lo, rp);
                    p2_issue(magH, z0 + z + 3, y0, lo, rh); }
        if (xok) p2_emit(P1, P2, P0, H1, H2, H0, acc);
        if (!more) break;
        ++z;
        p2_reduce(rp, P1); p2_reduce(rh, H1);
        more = (z + 1 < zn);
        if (more) { p2_issue(magP, z0 + z + 3, y0, lo, rp);
                    p2_issue(magH, z0 + z + 3, y0, lo, rh); }
        if (xok) p2_emit(P2, P0, P1, H2, H0, H1, acc);
        if (!more) break;
        ++z;
        p2_reduce(rp, P2); p2_reduce(rh, H2);
    }

    // block reduction: wave64 shuffle, then across the 4 waves via LDS
    for (int o = 32; o > 0; o >>= 1) acc += __shfl_down(acc, o, 64);
    __shared__ float sred[BDIM / 64];
    const int lane = threadIdx.x & 63, wv = threadIdx.x >> 6;
    if (lane == 0) sred[wv] = acc;
    __syncthreads();
    if (threadIdx.x == 0) {
        float t = 0.f;
#pragma unroll
        for (int i = 0; i < BDIM / 64; ++i) t += sred[i];
        partial[(size_t)b * 1200 + (size_t)zc * 120 + blockIdx.x] = t;
    }
}

// -------- Finalize: sum 2400 partials in double, write mean --------
__global__ __launch_bounds__(BDIM) void finalize_kernel(
    const float* __restrict__ partial, float* __restrict__ out)
{
    double a = 0.0;
    for (int i = threadIdx.x; i < 2400; i += BDIM) a += (double)partial[i];
    for (int o = 32; o > 0; o >>= 1) a += __shfl_down(a, o, 64);
    __shared__ double sd[BDIM / 64];
    const int lane = threadIdx.x & 63, wv = threadIdx.x >> 6;
    if (lane == 0) sd[wv] = a;
    __syncthreads();
    if (threadIdx.x == 0) {
        double t = 0.0;
#pragma unroll
        for (int i = 0; i < BDIM / 64; ++i) t += sd[i];
        out[0] = (float)(t / 13824000.0);
    }
}

extern "C" void kernel_launch(void* const* d_in, const int* in_sizes, int n_in,
                              void* d_out, int out_size, void* d_ws, size_t ws_size,
                              hipStream_t stream)
{
    const float* pred = (const float*)d_in[0];
    const float* hr   = (const float*)d_in[1];

    // ws layout: [0, 9.6KB): 2400 float partials (fully overwritten each call)
    //            [64KB, ...): mag buffers fp16; 2 buffers (29.1 MiB) sequential,
    //            4 buffers (58.2 MiB) merged-batch if ws_size allows.
    float* partial = (float*)d_ws;
    __half* magbase = (__half*)((char*)d_ws + 65536);

    const bool merged = ws_size >= (size_t)65536 + 4 * MAGSZ * sizeof(__half);
    if (merged) {
        sobel_mag_stream<<<dim3(124, 8, 4), BDIM, 0, stream>>>(pred, hr, magbase, 0);
        sobel2_stream<<<dim3(120, 10, 2), BDIM, 0, stream>>>(magbase, partial, 0);
    } else {
        for (int b = 0; b < 2; ++b) {
            sobel_mag_stream<<<dim3(124, 8, 2), BDIM, 0, stream>>>(pred, hr, magbase, b);
            sobel2_stream<<<dim3(120, 10, 1), BDIM, 0, stream>>>(magbase, partial, b);
        }
    }
    finalize_kernel<<<1, BDIM, 0, stream>>>(partial, (float*)d_out);
}